// Round 12
// baseline (29.442 us; speedup 1.0000x reference)
//
#include <hip/hip_runtime.h>

// QuantumTTEmbedding: TT-factorized embedding lookup.
// id -> (i,j,k) = (id/1600, (id/40)%40, id%40).
// Per half h (real/imag):
//   out[d][f][e] = sum_{r,s} c1[0][i][d][r] * c2[r][j][f][s] * c3[s][k][e][0]
// Output [N][256] f32, flat (h*128 + d*32 + f*8 + e).
//
// R7 mapping (proven): one wave per token; lane = (h,d,f,e-half),
// 4 outputs/lane -> one float4 store = 1KB contiguous per wave; rank-split
// phase 1 across the e0-pair (7 DS instrs/token) with DPP quad_perm.
// Proven: stores must stay 1KB contiguous (R4/R10); VALU/unroll null
// (R8/R9); fewer+longer write streams win (R11: 512blk/TPW32 -> -1.1us).
// R12 (single variable): 256 blocks, TPW=64. 2048 waves x 64KB runs,
// 1 block/CU (8 waves/CU). Stream-locality lever, step 2.

#define V1 20
#define V2 40
#define V3 40
#define D1 4
#define D2 4
#define D3 8
#define RNK 4

#define C1_SZ (V1*D1*RNK)          // 320 floats
#define C2_SZ (RNK*V2*D2*RNK)      // 2560 floats
#define C3_SZ (RNK*V3*D3)          // 1280 floats
#define HALF_SZ (C1_SZ + C2_SZ + C3_SZ)   // 4160
#define IMAG_OFF (HALF_SZ + 16)    // 4176: imag base == 16 mod 32 banks
#define LDS_FLOATS (IMAG_OFF + HALF_SZ)   // 8336 floats = 33.4 KB

#define TPW 64                     // tokens per wave
#define BLOCK 512                  // 8 waves/block; 1 block/CU -> 8 waves/CU

// quad_perm [1,0,3,2]: swap lanes differing in bit0 (the e0-pair). Pure VALU.
__device__ __forceinline__ float dpp_swap1(float x) {
    int xi = __builtin_bit_cast(int, x);
    int yi = __builtin_amdgcn_mov_dpp(xi, 0xB1, 0xF, 0xF, true);
    return __builtin_bit_cast(float, yi);
}

__global__ __launch_bounds__(BLOCK, 8) void tt_embed_kernel(
    const int* __restrict__ ids,
    const float* __restrict__ cr1, const float* __restrict__ cr2, const float* __restrict__ cr3,
    const float* __restrict__ ci1, const float* __restrict__ ci2, const float* __restrict__ ci3,
    float* __restrict__ out, int N)
{
    __shared__ __align__(16) float lds[LDS_FLOATS];

    // ---- issue this wave's id loads FIRST (hide under staging) ----
    const int lane = threadIdx.x & 63;
    const int wid  = blockIdx.x * (BLOCK / 64) + (threadIdx.x >> 6);
    const int t0   = wid * TPW;
    const int nv   = (N - t0 < TPW) ? (N - t0) : TPW;
    int id = 0;
    if (lane < nv) id = ids[t0 + lane];

    // ---- stage cores into LDS, float4-vectorized ----
    {
        float4*       l4r = (float4*)lds;
        float4*       l4i = (float4*)(lds + IMAG_OFF);
        const float4* s1r = (const float4*)cr1; const float4* s1i = (const float4*)ci1;
        const float4* s2r = (const float4*)cr2; const float4* s2i = (const float4*)ci2;
        const float4* s3r = (const float4*)cr3; const float4* s3i = (const float4*)ci3;
        for (int idx = threadIdx.x; idx < C1_SZ/4; idx += BLOCK) {
            l4r[idx] = s1r[idx]; l4i[idx] = s1i[idx];
        }
        for (int idx = threadIdx.x; idx < C2_SZ/4; idx += BLOCK) {
            l4r[C1_SZ/4 + idx] = s2r[idx]; l4i[C1_SZ/4 + idx] = s2i[idx];
        }
        for (int idx = threadIdx.x; idx < C3_SZ/4; idx += BLOCK) {
            l4r[(C1_SZ+C2_SZ)/4 + idx] = s3r[idx]; l4i[(C1_SZ+C2_SZ)/4 + idx] = s3i[idx];
        }
    }

    // ---- decode id -> packed LDS float-offsets (overlaps staging) ----
    int packed = 0;
    if (lane < nv) {
        const int k  = id % V3;
        const int ij = id / V3;
        const int j  = ij % V2;
        const int i  = ij / V2;
        // i*16 (9b) | j*16 << 9 (10b) | k*8 << 19 (9b)
        packed = (i * (D1*RNK)) | ((j * (D2*RNK)) << 9) | ((k * D3) << 19);
    }

    __syncthreads();

    // ---- lane decomposition: one wave per token, 4 outputs per lane ----
    const int half = lane >> 5;          // 0 = real, 1 = imag
    const int q    = lane & 31;
    const int d    = q >> 3;             // 0..3
    const int f    = (q >> 1) & 3;       // 0..3
    const int e0   = (q & 1) * 4;        // 0 or 4
    const int roff = (q & 1) * 2;        // this lane's r-pair: {0,1} or {2,3}

    const float* base = lds + half * IMAG_OFF;
    const float* B1 = base + d * RNK + roff;             // + io -> g1[d][roff..roff+1]
    const float* B2 = base + C1_SZ + f * RNK;            // + jo + r*640 -> g2[r][f][0..3]
    const float* B3 = base + C1_SZ + C2_SZ + e0;         // + ko + s*320 -> g3[s][e0..e0+3]

    float* outp = out + (size_t)t0 * 256 + lane * 4;

    #pragma unroll 1
    for (int it = 0; it < nv; ++it) {
        const int p  = __builtin_amdgcn_readlane(packed, it);  // SGPR broadcast
        const int io = p & 0x1ff;
        const int jo = (p >> 9) & 0x3ff;
        const int ko = (p >> 19);

        // phase 1 (rank-split): partial[s] = sum_{r in pair} g1[d][r]*g2[r][f][s]
        const float2 g1p = *reinterpret_cast<const float2*>(B1 + io);
        const float* p2  = B2 + jo;
        const float4 aA  = *reinterpret_cast<const float4*>(p2 +  roff      * (V2*D2*RNK));
        const float4 aB  = *reinterpret_cast<const float4*>(p2 + (roff + 1) * (V2*D2*RNK));
        float t0p = g1p.x*aA.x + g1p.y*aB.x;
        float t1p = g1p.x*aA.y + g1p.y*aB.y;
        float t2p = g1p.x*aA.z + g1p.y*aB.z;
        float t3p = g1p.x*aA.w + g1p.y*aB.w;
        // exchange with e0-partner (lane^1) and sum -> full tmp[s]
        const float tmp0 = t0p + dpp_swap1(t0p);
        const float tmp1 = t1p + dpp_swap1(t1p);
        const float tmp2 = t2p + dpp_swap1(t2p);
        const float tmp3 = t3p + dpp_swap1(t3p);

        // phase 2: out[e] = sum_s tmp[s] * g3[s][e0+e]
        const float* p3 = B3 + ko;
        const float4 b0 = *reinterpret_cast<const float4*>(p3);
        const float4 b1 = *reinterpret_cast<const float4*>(p3 +     V3*D3);
        const float4 b2 = *reinterpret_cast<const float4*>(p3 + 2 * V3*D3);
        const float4 b3 = *reinterpret_cast<const float4*>(p3 + 3 * V3*D3);
        float4 o;
        o.x = tmp0*b0.x + tmp1*b1.x + tmp2*b2.x + tmp3*b3.x;
        o.y = tmp0*b0.y + tmp1*b1.y + tmp2*b2.y + tmp3*b3.y;
        o.z = tmp0*b0.z + tmp1*b1.z + tmp2*b2.z + tmp3*b3.z;
        o.w = tmp0*b0.w + tmp1*b1.w + tmp2*b2.w + tmp3*b3.w;

        *reinterpret_cast<float4*>(outp) = o;
        outp += 256;
    }
}

extern "C" void kernel_launch(void* const* d_in, const int* in_sizes, int n_in,
                              void* d_out, int out_size, void* d_ws, size_t ws_size,
                              hipStream_t stream) {
    const int*   ids = (const int*)d_in[0];
    const float* cr1 = (const float*)d_in[1];
    const float* cr2 = (const float*)d_in[2];
    const float* cr3 = (const float*)d_in[3];
    const float* ci1 = (const float*)d_in[4];
    const float* ci2 = (const float*)d_in[5];
    const float* ci3 = (const float*)d_in[6];
    float* out = (float*)d_out;

    const int N = in_sizes[0];
    const int tokens_per_block = (BLOCK / 64) * TPW;                   // 512
    const int blocks = (N + tokens_per_block - 1) / tokens_per_block;  // 256 @ N=131072

    tt_embed_kernel<<<blocks, BLOCK, 0, stream>>>(ids, cr1, cr2, cr3, ci1, ci2, ci3, out, N);
}

// Round 13
// 27.736 us; speedup vs baseline: 1.0615x; 1.0615x over previous
//
#include <hip/hip_runtime.h>

// QuantumTTEmbedding: TT-factorized embedding lookup.
// id -> (i,j,k) = (id/1600, (id/40)%40, id%40).
// Per half h (real/imag):
//   out[d][f][e] = sum_{r,s} c1[0][i][d][r] * c2[r][j][f][s] * c3[s][k][e][0]
// Output [N][256] f32, flat (h*128 + d*32 + f*8 + e).
//
// R11 shape (best, 27.9us): 512 blocks x 8 waves, TPW=32, 16 waves/CU.
// One wave per token; lane = (h,d,f,e-half), 4 outputs/lane -> one float4
// store = 1KB contiguous per wave; rank-split phase 1 across the e0-pair
// (7 DS instrs/token) with DPP quad_perm exchange.
// Proven: stores must stay 1KB contiguous (R4/R10); VALU null (R8);
// occupancy optimum 16 waves/CU (29.0@32, 27.9@16, 29.4@8); LDS instr
// floor = 7/token for this layout.
// R13 (single variable): #pragma unroll 2 - at 16 waves/CU the TLP margin
// is gone (R12), so cross-iteration ILP may now cover DS latency (R9's
// null was at 32 waves/CU).

#define V1 20
#define V2 40
#define V3 40
#define D1 4
#define D2 4
#define D3 8
#define RNK 4

#define C1_SZ (V1*D1*RNK)          // 320 floats
#define C2_SZ (RNK*V2*D2*RNK)      // 2560 floats
#define C3_SZ (RNK*V3*D3)          // 1280 floats
#define HALF_SZ (C1_SZ + C2_SZ + C3_SZ)   // 4160
#define IMAG_OFF (HALF_SZ + 16)    // 4176: imag base == 16 mod 32 banks
#define LDS_FLOATS (IMAG_OFF + HALF_SZ)   // 8336 floats = 33.4 KB

#define TPW 32                     // tokens per wave
#define BLOCK 512                  // 8 waves/block; 2 blocks/CU -> 16 waves/CU

// quad_perm [1,0,3,2]: swap lanes differing in bit0 (the e0-pair). Pure VALU.
__device__ __forceinline__ float dpp_swap1(float x) {
    int xi = __builtin_bit_cast(int, x);
    int yi = __builtin_amdgcn_mov_dpp(xi, 0xB1, 0xF, 0xF, true);
    return __builtin_bit_cast(float, yi);
}

__global__ __launch_bounds__(BLOCK, 8) void tt_embed_kernel(
    const int* __restrict__ ids,
    const float* __restrict__ cr1, const float* __restrict__ cr2, const float* __restrict__ cr3,
    const float* __restrict__ ci1, const float* __restrict__ ci2, const float* __restrict__ ci3,
    float* __restrict__ out, int N)
{
    __shared__ __align__(16) float lds[LDS_FLOATS];

    // ---- issue this wave's id loads FIRST (hide under staging) ----
    const int lane = threadIdx.x & 63;
    const int wid  = blockIdx.x * (BLOCK / 64) + (threadIdx.x >> 6);
    const int t0   = wid * TPW;
    const int nv   = (N - t0 < TPW) ? (N - t0) : TPW;
    int id = 0;
    if (lane < TPW && lane < nv) id = ids[t0 + lane];

    // ---- stage cores into LDS, float4-vectorized ----
    {
        float4*       l4r = (float4*)lds;
        float4*       l4i = (float4*)(lds + IMAG_OFF);
        const float4* s1r = (const float4*)cr1; const float4* s1i = (const float4*)ci1;
        const float4* s2r = (const float4*)cr2; const float4* s2i = (const float4*)ci2;
        const float4* s3r = (const float4*)cr3; const float4* s3i = (const float4*)ci3;
        for (int idx = threadIdx.x; idx < C1_SZ/4; idx += BLOCK) {
            l4r[idx] = s1r[idx]; l4i[idx] = s1i[idx];
        }
        for (int idx = threadIdx.x; idx < C2_SZ/4; idx += BLOCK) {
            l4r[C1_SZ/4 + idx] = s2r[idx]; l4i[C1_SZ/4 + idx] = s2i[idx];
        }
        for (int idx = threadIdx.x; idx < C3_SZ/4; idx += BLOCK) {
            l4r[(C1_SZ+C2_SZ)/4 + idx] = s3r[idx]; l4i[(C1_SZ+C2_SZ)/4 + idx] = s3i[idx];
        }
    }

    // ---- decode id -> packed LDS float-offsets (overlaps staging) ----
    int packed = 0;
    if (lane < TPW && lane < nv) {
        const int k  = id % V3;
        const int ij = id / V3;
        const int j  = ij % V2;
        const int i  = ij / V2;
        // i*16 (9b) | j*16 << 9 (10b) | k*8 << 19 (9b)
        packed = (i * (D1*RNK)) | ((j * (D2*RNK)) << 9) | ((k * D3) << 19);
    }

    __syncthreads();

    // ---- lane decomposition: one wave per token, 4 outputs per lane ----
    const int half = lane >> 5;          // 0 = real, 1 = imag
    const int q    = lane & 31;
    const int d    = q >> 3;             // 0..3
    const int f    = (q >> 1) & 3;       // 0..3
    const int e0   = (q & 1) * 4;        // 0 or 4
    const int roff = (q & 1) * 2;        // this lane's r-pair: {0,1} or {2,3}

    const float* base = lds + half * IMAG_OFF;
    const float* B1 = base + d * RNK + roff;             // + io -> g1[d][roff..roff+1]
    const float* B2 = base + C1_SZ + f * RNK;            // + jo + r*640 -> g2[r][f][0..3]
    const float* B3 = base + C1_SZ + C2_SZ + e0;         // + ko + s*320 -> g3[s][e0..e0+3]

    float* outp = out + (size_t)t0 * 256 + lane * 4;

    #pragma unroll 2
    for (int it = 0; it < nv; ++it) {
        const int p  = __builtin_amdgcn_readlane(packed, it);  // SGPR broadcast
        const int io = p & 0x1ff;
        const int jo = (p >> 9) & 0x3ff;
        const int ko = (p >> 19);

        // phase 1 (rank-split): partial[s] = sum_{r in pair} g1[d][r]*g2[r][f][s]
        const float2 g1p = *reinterpret_cast<const float2*>(B1 + io);
        const float* p2  = B2 + jo;
        const float4 aA  = *reinterpret_cast<const float4*>(p2 +  roff      * (V2*D2*RNK));
        const float4 aB  = *reinterpret_cast<const float4*>(p2 + (roff + 1) * (V2*D2*RNK));
        float t0p = g1p.x*aA.x + g1p.y*aB.x;
        float t1p = g1p.x*aA.y + g1p.y*aB.y;
        float t2p = g1p.x*aA.z + g1p.y*aB.z;
        float t3p = g1p.x*aA.w + g1p.y*aB.w;
        // exchange with e0-partner (lane^1) and sum -> full tmp[s]
        const float tmp0 = t0p + dpp_swap1(t0p);
        const float tmp1 = t1p + dpp_swap1(t1p);
        const float tmp2 = t2p + dpp_swap1(t2p);
        const float tmp3 = t3p + dpp_swap1(t3p);

        // phase 2: out[e] = sum_s tmp[s] * g3[s][e0+e]
        const float* p3 = B3 + ko;
        const float4 b0 = *reinterpret_cast<const float4*>(p3);
        const float4 b1 = *reinterpret_cast<const float4*>(p3 +     V3*D3);
        const float4 b2 = *reinterpret_cast<const float4*>(p3 + 2 * V3*D3);
        const float4 b3 = *reinterpret_cast<const float4*>(p3 + 3 * V3*D3);
        float4 o;
        o.x = tmp0*b0.x + tmp1*b1.x + tmp2*b2.x + tmp3*b3.x;
        o.y = tmp0*b0.y + tmp1*b1.y + tmp2*b2.y + tmp3*b3.y;
        o.z = tmp0*b0.z + tmp1*b1.z + tmp2*b2.z + tmp3*b3.z;
        o.w = tmp0*b0.w + tmp1*b1.w + tmp2*b2.w + tmp3*b3.w;

        *reinterpret_cast<float4*>(outp) = o;
        outp += 256;
    }
}

extern "C" void kernel_launch(void* const* d_in, const int* in_sizes, int n_in,
                              void* d_out, int out_size, void* d_ws, size_t ws_size,
                              hipStream_t stream) {
    const int*   ids = (const int*)d_in[0];
    const float* cr1 = (const float*)d_in[1];
    const float* cr2 = (const float*)d_in[2];
    const float* cr3 = (const float*)d_in[3];
    const float* ci1 = (const float*)d_in[4];
    const float* ci2 = (const float*)d_in[5];
    const float* ci3 = (const float*)d_in[6];
    float* out = (float*)d_out;

    const int N = in_sizes[0];
    const int tokens_per_block = (BLOCK / 64) * TPW;                   // 256
    const int blocks = (N + tokens_per_block - 1) / tokens_per_block;  // 512 @ N=131072

    tt_embed_kernel<<<blocks, BLOCK, 0, stream>>>(ids, cr1, cr2, cr3, ci1, ci2, ci3, out, N);
}